// Round 1
// 73.565 us; speedup vs baseline: 1.0630x; 1.0630x over previous
//
#include <hip/hip_runtime.h>
#include <math.h>

#define CH 1
#define H 1024
#define NN 64
#define N_SSM 1024
#define SEQ_L 2048
#define TPB 256
#define LPT 8     // l-values per thread; SEQ_L / TPB == LPT
#define TSTR 68   // padded row stride (floats): 68%32=4 banks apart per row, 272B is 8B-aligned

typedef float v2f __attribute__((ext_vector_type(2)));

__global__ __launch_bounds__(TPB) void sskd_kernel(
    const float* __restrict__ C_ri, const float* __restrict__ log_dt,
    const float* __restrict__ B_ri, const float* __restrict__ inv_A_real,
    const float* __restrict__ A_imag, float* __restrict__ out)
{
    const int h   = blockIdx.x;
    const int tid = threadIdx.x;

    // Power tables: U1[t1][n] = 2Ct*w^(128*t1), Ud[t1][n] = 2Ct*dA*w^(128*t1),
    //               T0[t0][n] = w^(8*t0).  w := dA.  x(8*tid) = Re(U1[t1]*T0[t0]).
    __shared__ __align__(16) float sU1r[16][TSTR], sU1i[16][TSTR];
    __shared__ __align__(16) float sVdr[16][TSTR], sVdi[16][TSTR];
    __shared__ __align__(16) float sT0r[16][TSTR], sT0i[16][TSTR];
    __shared__ __align__(16) float sP[NN], sQ[NN];
    __shared__ __align__(16) float sW8r[NN], sW8i[NN], sW128r[NN], sW128i[NN];
    __shared__ __align__(16) float sCtr[NN], sCti[NN], sCdr[NN], sCdi[NN];

    // ---- Stage A (one wave): per-n params + w^8, w^128 by exact squaring ----
    if (tid < NN) {
        const int n = tid;
        const float dt  = __expf(log_dt[h]);
        const float Ar  = -__expf(inv_A_real[h * NN + n]);
        const float Ai  = A_imag[h * NN + n];
        const float dtAr = Ar * dt, dtAi = Ai * dt;
        const float den_r = 1.0f - 0.5f * dtAr;
        const float den_i = -0.5f * dtAi;
        const float num_r = 1.0f + 0.5f * dtAr;
        const float num_i = 0.5f * dtAi;
        const float inv_den = 1.0f / (den_r * den_r + den_i * den_i);
        const float dA_r = (num_r * den_r + num_i * den_i) * inv_den;
        const float dA_i = (num_i * den_r - num_r * den_i) * inv_den;
        const int   bh = h % N_SSM;                       // rep==1 here, kept general
        const float Br = B_ri[(bh * NN + n) * 2 + 0];
        const float Bi = B_ri[(bh * NN + n) * 2 + 1];
        const float Cr = C_ri[(h * NN + n) * 2 + 0];
        const float Ci = C_ri[(h * NN + n) * 2 + 1];
        const float BCr = Br * Cr - Bi * Ci;
        const float BCi = Br * Ci + Bi * Cr;
        const float sc = 2.0f * dt * inv_den;             // fold final 2*Re(..) in
        const float ctr = (BCr * den_r + BCi * den_i) * sc;
        const float cti = (BCi * den_r - BCr * den_i) * sc;
        sCtr[n] = ctr; sCti[n] = cti;
        sCdr[n] = ctr * dA_r - cti * dA_i;                // ct*dA
        sCdi[n] = ctr * dA_i + cti * dA_r;
        sP[n] = 2.0f * dA_r;                              // x_l = p*x_{l-1} - q*x_{l-2}
        sQ[n] = dA_r * dA_r + dA_i * dA_i;                // |dA|^2 < 1 always
        // squaring chain: w^2 -> w^4 -> w^8 -> ... -> w^128
        float wr = dA_r * dA_r - dA_i * dA_i, wi = 2.0f * dA_r * dA_i;   // w^2
        float tr = wr * wr - wi * wi,         ti = 2.0f * wr * wi;       // w^4
        wr = tr * tr - ti * ti;               wi = 2.0f * tr * ti;       // w^8
        sW8r[n] = wr; sW8i[n] = wi;
        tr = wr * wr - wi * wi;               ti = 2.0f * wr * wi;       // w^16
        wr = tr * tr - ti * ti;               wi = 2.0f * tr * ti;       // w^32
        tr = wr * wr - wi * wi;               ti = 2.0f * wr * wi;       // w^64
        wr = tr * tr - ti * ti;               wi = 2.0f * tr * ti;       // w^128
        sW128r[n] = wr; sW128i[n] = wi;
    }
    __syncthreads();

    // ---- Stage B (all 256 threads): fill tables. Wave g handles rows 4g..4g+3 ----
    {
        const int n = tid & 63;
        const int g = tid >> 6;                            // wave-uniform
        // U rows: W = w128^(4g), then chain by *w128
        {
            const float wr = sW128r[n], wi = sW128i[n];
            const float ctr = sCtr[n], cti = sCti[n];
            const float cdr = sCdr[n], cdi = sCdi[n];
            const float b2r = wr*wr - wi*wi,   b2i = 2.0f*wr*wi;    // w128^2
            const float b4r = b2r*b2r - b2i*b2i, b4i = 2.0f*b2r*b2i; // w128^4
            const float b8r = b4r*b4r - b4i*b4i, b8i = 2.0f*b4r*b4i; // w128^8
            float Wr = 1.0f, Wi = 0.0f;
            if (g & 1) { Wr = b4r; Wi = b4i; }
            if (g & 2) { const float t = Wr*b8r - Wi*b8i; Wi = Wr*b8i + Wi*b8r; Wr = t; }
            #pragma unroll
            for (int i = 0; i < 4; ++i) {
                const int t1 = 4 * g + i;
                sU1r[t1][n] = ctr*Wr - cti*Wi;
                sU1i[t1][n] = ctr*Wi + cti*Wr;
                sVdr[t1][n] = cdr*Wr - cdi*Wi;
                sVdi[t1][n] = cdr*Wi + cdi*Wr;
                const float t = Wr*wr - Wi*wi; Wi = Wr*wi + Wi*wr; Wr = t;
            }
        }
        // T0 rows: V = w8^(4g), then chain by *w8
        {
            const float ur = sW8r[n], ui = sW8i[n];
            const float a2r = ur*ur - ui*ui,     a2i = 2.0f*ur*ui;     // w8^2
            const float a4r = a2r*a2r - a2i*a2i, a4i = 2.0f*a2r*a2i;   // w8^4
            const float a8r = a4r*a4r - a4i*a4i, a8i = 2.0f*a4r*a4i;   // w8^8
            float Vr = 1.0f, Vi = 0.0f;
            if (g & 1) { Vr = a4r; Vi = a4i; }
            if (g & 2) { const float t = Vr*a8r - Vi*a8i; Vi = Vr*a8i + Vi*a8r; Vr = t; }
            #pragma unroll
            for (int i = 0; i < 4; ++i) {
                const int t0 = 4 * g + i;
                sT0r[t0][n] = Vr;
                sT0i[t0][n] = Vi;
                const float t = Vr*ur - Vi*ui; Vi = Vr*ui + Vi*ur; Vr = t;
            }
        }
    }
    __syncthreads();

    // ---- Main loop: no transcendentals. 24 pk-ops + 8 ds_read_b64 per 2 n's ----
    const int t1 = tid >> 4;
    const int t0 = tid & 15;

    v2f acc[LPT];
    #pragma unroll
    for (int k = 0; k < LPT; ++k) acc[k] = (v2f)(0.0f);

    #pragma unroll 2
    for (int m = 0; m < NN / 2; ++m) {
        const v2f ur = *(const v2f*)&sU1r[t1][2 * m];
        const v2f ui = *(const v2f*)&sU1i[t1][2 * m];
        const v2f vr = *(const v2f*)&sVdr[t1][2 * m];
        const v2f vi = *(const v2f*)&sVdi[t1][2 * m];
        const v2f br = *(const v2f*)&sT0r[t0][2 * m];
        const v2f bi = *(const v2f*)&sT0i[t0][2 * m];
        const v2f p  = *(const v2f*)&sP[2 * m];
        const v2f q  = *(const v2f*)&sQ[2 * m];

        v2f x2 = ur * br - ui * bi;    // x(l0)   = Re(2Ct    * w^l0)
        v2f x1 = vr * br - vi * bi;    // x(l0+1) = Re(2Ct*dA * w^l0)
        acc[0] += x2;
        acc[1] += x1;
        #pragma unroll
        for (int k = 2; k < LPT; ++k) {
            const v2f xn = p * x1 - q * x2;   // v_pk_mul + v_pk_fma
            acc[k] += xn;
            x2 = x1;
            x1 = xn;
        }
    }

    float4 o0, o1;
    o0.x = acc[0].x + acc[0].y;
    o0.y = acc[1].x + acc[1].y;
    o0.z = acc[2].x + acc[2].y;
    o0.w = acc[3].x + acc[3].y;
    o1.x = acc[4].x + acc[4].y;
    o1.y = acc[5].x + acc[5].y;
    o1.z = acc[6].x + acc[6].y;
    o1.w = acc[7].x + acc[7].y;
    float4* o = (float4*)(out + (size_t)h * SEQ_L + tid * LPT);
    o[0] = o0;
    o[1] = o1;
}

extern "C" void kernel_launch(void* const* d_in, const int* in_sizes, int n_in,
                              void* d_out, int out_size, void* d_ws, size_t ws_size,
                              hipStream_t stream) {
    const float* C_ri       = (const float*)d_in[0];
    const float* log_dt     = (const float*)d_in[1];
    const float* B_ri       = (const float*)d_in[2];
    const float* inv_A_real = (const float*)d_in[3];
    const float* A_imag     = (const float*)d_in[4];
    float* out = (float*)d_out;

    sskd_kernel<<<dim3(H), dim3(TPB), 0, stream>>>(
        C_ri, log_dt, B_ri, inv_A_real, A_imag, out);
}